// Round 22
// baseline (9532.413 us; speedup 1.0000x reference)
//
#include <hip/hip_runtime.h>

typedef __bf16 bf16x8 __attribute__((ext_vector_type(8)));
typedef float f32x4 __attribute__((ext_vector_type(4)));
typedef unsigned short u16;
typedef unsigned u32;
typedef unsigned long long u64;

#define NSTEP 512

#define AL(p)   __hip_atomic_load((p), __ATOMIC_RELAXED, __HIP_MEMORY_SCOPE_AGENT)
#define AS(p,v) __hip_atomic_store((p), (v), __ATOMIC_RELAXED, __HIP_MEMORY_SCOPE_AGENT)

__device__ __forceinline__ u16 f2bf(float f) {
  union { float f; unsigned u; } x; x.f = f;
  return (u16)((x.u + 0x7fffu + ((x.u >> 16) & 1u)) >> 16);
}

// prep A (tagged): zero ALL tagged h buffers — tags must reset every call so
// graph replays re-do the real waiting (no cross-replay stale-accept).
__global__ void prepA_kernel(u64* __restrict__ H64) {
  size_t i = (size_t)blockIdx.x * blockDim.x + threadIdx.x;
  size_t stride = (size_t)gridDim.x * blockDim.x;
  for (size_t k = i; k < (size_t)NSTEP * 32768; k += stride) H64[k] = 0;
}

// prep B (fallback r18): zero h buffer 0 + per-wave epoch flags
__global__ void prepB_kernel(u64* __restrict__ H0, int* __restrict__ F) {
  int i = blockIdx.x * blockDim.x + threadIdx.x;
  if (i < 16384) AS(H0 + i, 0ULL);
  if (i < 32768) AS(&F[i], 0);
}

// A1[t*64+b][512] bf16 embedding gather
__global__ void gather_kernel(const int* __restrict__ sent, const float* __restrict__ emb,
                              u16* __restrict__ A1) {
  int row = blockIdx.x * 4 + (threadIdx.x >> 6);   // t*64+b
  int lane = threadIdx.x & 63;
  int t = row >> 6, b = row & 63;
  int idx = sent[b * 512 + t];
  const float* src = emb + (size_t)idx * 512 + lane * 8;
  u16* dst = A1 + (size_t)row * 512 + lane * 8;
  #pragma unroll
  for (int k = 0; k < 8; ++k) dst[k] = f2bf(src[k]);
}

// ================= TAGGED DATAFLOW KERNEL (tier A) =================
// 256 WGs x 256 thr, WG j owns h cols [j*4,j*4+4), gates rb = g*4+nn = lr.
// h exchange: per-step FRESH buffers of u64 words [epoch:32 | h(2s+1):bf16 | h(2s):bf16].
// Producer: sc1-store tagged words — NO vmcnt, NO flag, NO syncthreads.
// Consumer: cached fills (1 RT), tag check in registers, UC retry for stale words.
__global__ void __launch_bounds__(256, 1)
lstm_tag_kernel(const u16* __restrict__ A1,
                const float* __restrict__ wih, const float* __restrict__ whh,
                const float* __restrict__ bih, const float* __restrict__ bhh,
                u64* __restrict__ H64, float* __restrict__ out) {
  __shared__ u16 wlds[48 * 16 * 36];        // 55296 B, stride-36 pad

  const int j   = blockIdx.x;
  const int tid = threadIdx.x;
  const int w   = tid >> 6;            // wave = batch tile 0..3
  const int l   = tid & 63;
  const int lr  = l & 15, lk = l >> 4;
  const int g   = lr >> 2, nn = lr & 3;
  const int wrow = g * 1024 + j * 4 + nn;

  // ---- stage ALL weights fp32->bf16 into padded LDS (once) ----
  for (int task = tid; task < 3072; task += 256) {
    int kk = task >> 6;
    int rem = task & 63;
    int rb = rem >> 2, q = rem & 3;
    int row = (rb >> 2) * 1024 + j * 4 + (rb & 3);
    const float* src = (kk < 16) ? (wih + (size_t)row * 512 + kk * 32 + q * 8)
                                 : (whh + (size_t)row * 1024 + (kk - 16) * 32 + q * 8);
    u16* dst = wlds + (kk * 16 + rb) * 36 + q * 8;
    #pragma unroll
    for (int e = 0; e < 8; ++e) dst[e] = f2bf(src[e]);
  }
  __syncthreads();

  const float bias = bih[wrow] + bhh[wrow];
  const float sca = (g == 2) ? 2.f : 1.f;
  const float bd  = (g == 2) ? -1.f : 0.f;
  const int arow = w * 16 + lr;
  const u16* bx = wlds + lr * 36 + lk * 8;

  float cst[4] = {0.f, 0.f, 0.f, 0.f};

  union AF { bf16x8 v; u32 d[4]; };

#define LD8C(BUF, BAD, CH)                                                  \
  { BAD = 0;                                                                \
    _Pragma("unroll")                                                       \
    for (int r = 0; r < 8; ++r) {                                           \
      const u64* p = hp64 + ((CH) * 8 + r) * 16 + lk * 4;                   \
      u64 w0 = p[0], w1 = p[1], w2 = p[2], w3 = p[3];                       \
      BUF[r].d[0] = (u32)w0; BUF[r].d[1] = (u32)w1;                         \
      BUF[r].d[2] = (u32)w2; BUF[r].d[3] = (u32)w3;                         \
      BAD |= ((u32)(w0 >> 32) ^ tu) | ((u32)(w1 >> 32) ^ tu)                \
           | ((u32)(w2 >> 32) ^ tu) | ((u32)(w3 >> 32) ^ tu);               \
    } }
#define RTY(BUF, BAD, CH)                                                   \
  while (BAD) {                                                             \
    __builtin_amdgcn_s_sleep(2);                                            \
    BAD = 0;                                                                \
    _Pragma("unroll")                                                       \
    for (int r = 0; r < 8; ++r) {                                           \
      const u64* p = hp64 + ((CH) * 8 + r) * 16 + lk * 4;                   \
      u64 w0 = AL(p), w1 = AL(p + 1), w2 = AL(p + 2), w3 = AL(p + 3);       \
      BUF[r].d[0] = (u32)w0; BUF[r].d[1] = (u32)w1;                         \
      BUF[r].d[2] = (u32)w2; BUF[r].d[3] = (u32)w3;                         \
      BAD |= ((u32)(w0 >> 32) ^ tu) | ((u32)(w1 >> 32) ^ tu)                \
           | ((u32)(w2 >> 32) ^ tu) | ((u32)(w3 >> 32) ^ tu);               \
    } }
#define MM8T(ACC, BUF, W0)                                                  \
  { _Pragma("unroll")                                                       \
    for (int r = 0; r < 8; ++r) {                                           \
      bf16x8 b = *(const bf16x8*)(bx + ((W0) + r) * 576);                   \
      ACC = __builtin_amdgcn_mfma_f32_16x16x32_bf16(BUF[r].v, b, ACC, 0, 0, 0); \
    } }

  #pragma unroll 1
  for (int t = 0; t < NSTEP; ++t) {
    const u32 tu = (u32)t;
    const u64* hp64 = H64 + (size_t)t * 32768 + (size_t)arow * 512;
    // x-projection JIT (A1 cached, L2-hot across 256 WGs)
    f32x4 acx = { bias, bias, bias, bias };
    {
      const u16* ap = A1 + ((size_t)t * 64 + arow) * 512 + lk * 8;
      #pragma unroll
      for (int kk = 0; kk < 16; ++kk) {
        bf16x8 a = *(const bf16x8*)(ap + kk * 32);
        bf16x8 b = *(const bf16x8*)(bx + kk * 576);
        acx = __builtin_amdgcn_mfma_f32_16x16x32_bf16(a, b, acx, 0, 0, 0);
      }
    }
    // h-projection: optimistic cached fills, tag-checked, UC retry for laggards
    AF ha[8], hb[8], hc[8];
    u32 bad0, bad1, bad2, bad3;
    f32x4 ac1 = { 0.f, 0.f, 0.f, 0.f };
    f32x4 ac2 = { 0.f, 0.f, 0.f, 0.f };
    LD8C(ha, bad0, 0);
    LD8C(hb, bad1, 1);
    LD8C(hc, bad2, 2);
    RTY(ha, bad0, 0);
    MM8T(ac1, ha, 16);
    LD8C(ha, bad3, 3);          // reuse ha for chunk 3
    RTY(hb, bad1, 1);
    MM8T(ac2, hb, 24);
    RTY(hc, bad2, 2);
    MM8T(ac1, hc, 32);
    RTY(ha, bad3, 3);
    MM8T(ac2, ha, 40);

    // activations + state update; lanes lr<4 own (rows lk*4+r, col lr)
    float hv4[4], cn4[4];
    #pragma unroll
    for (int r = 0; r < 4; ++r) {
      float xv = acx[r] + ac1[r] + ac2[r];
      float act = sca / (1.f + __expf(-sca * xv)) + bd;
      float gg = __shfl_xor(act, 8);
      float ff = __shfl_xor(act, 4);
      float oo = __shfl_xor(act, 12);
      float cn = ff * cst[r] + act * gg;
      cst[r] = cn;
      float tc = 2.f / (1.f + __expf(-2.f * cn)) - 1.f;
      hv4[r] = oo * tc;
      cn4[r] = cn;
    }

    if (t == NSTEP - 1) {
      if (lr < 4) {
        #pragma unroll
        for (int r = 0; r < 4; ++r) {
          int R = w * 16 + lk * 4 + r;
          out[(size_t)R * 1024 + j * 4 + lr]          = hv4[r];
          out[65536 + (size_t)R * 1024 + j * 4 + lr]  = hv4[r];
          out[131072 + (size_t)R * 1024 + j * 4 + lr] = cn4[r];
        }
      }
    } else {
      // producer: tagged sc1 stores — data IS the flag; fire and forget
      const u32 tag = (u32)(t + 1);
      u64* Hn = H64 + (size_t)(t + 1) * 32768;
      #pragma unroll
      for (int r = 0; r < 4; ++r) {
        float hpart = __shfl_xor(hv4[r], 1);     // partner column's h
        if (lr < 4 && !(lr & 1)) {
          int R = w * 16 + lk * 4 + r;
          u64 pk = ((u64)tag << 32) | ((u32)f2bf(hpart) << 16) | (u32)f2bf(hv4[r]);
          AS(Hn + (size_t)R * 512 + j * 2 + (lr >> 1), pk);
        }
      }
    }
  }
#undef LD8C
#undef RTY
#undef MM8T
}

// ================= FALLBACK KERNEL (tier B = proven r18) =================
__global__ void __launch_bounds__(256, 2)
lstm_fb_kernel(const u16* __restrict__ A1,
               const float* __restrict__ wih, const float* __restrict__ whh,
               const float* __restrict__ bih, const float* __restrict__ bhh,
               u16* __restrict__ H, float* __restrict__ out, int* __restrict__ F) {
  __shared__ u16 wlds[48 * 16 * 36];
  __shared__ alignas(8) u16 hx[4][16][4];

  const int j   = blockIdx.x;
  const int tid = threadIdx.x;
  const int w   = tid >> 6;
  const int l   = tid & 63;
  const int lr  = l & 15, lk = l >> 4;
  const int g   = lr >> 2, nn = lr & 3;
  const int wrow = g * 1024 + j * 4 + nn;

  for (int task = tid; task < 3072; task += 256) {
    int kk = task >> 6;
    int rem = task & 63;
    int rb = rem >> 2, q = rem & 3;
    int row = (rb >> 2) * 1024 + j * 4 + (rb & 3);
    const float* src = (kk < 16) ? (wih + (size_t)row * 512 + kk * 32 + q * 8)
                                 : (whh + (size_t)row * 1024 + (kk - 16) * 32 + q * 8);
    u16* dst = wlds + (kk * 16 + rb) * 36 + q * 8;
    #pragma unroll
    for (int e = 0; e < 8; ++e) dst[e] = f2bf(src[e]);
  }
  __syncthreads();

  const float bias = bih[wrow] + bhh[wrow];
  const float sca = (g == 2) ? 2.f : 1.f;
  const float bd  = (g == 2) ? -1.f : 0.f;
  const int arow = w * 16 + lr;
  const u16* bx = wlds + lr * 36 + lk * 8;

  float cst[4] = {0.f, 0.f, 0.f, 0.f};

  bf16x8 ax[16];
  {
    const u16* apre = A1 + (size_t)arow * 512 + lk * 8;
    #pragma unroll
    for (int kk = 0; kk < 16; ++kk) ax[kk] = *(const bf16x8*)(apre + kk * 32);
  }

  union AF { bf16x8 v; u64 q[2]; };

#define FADDR(c) (F + (((c) * 64 + l) * 128) + w * 32)
#define WAITV(vv, c)                                                        \
  { while (vv < t) { __builtin_amdgcn_s_sleep(1); vv = AL(FADDR(c)); } }
#define LD8(BUF, CH)                                                        \
  { _Pragma("unroll")                                                       \
    for (int r = 0; r < 8; ++r)                                             \
      BUF[r].v = *(const bf16x8*)(hp + (CH) * 256 + r * 32); }
#define MM8(ACC, BUF, W0)                                                   \
  { _Pragma("unroll")                                                       \
    for (int r = 0; r < 8; ++r) {                                           \
      bf16x8 b = *(const bf16x8*)(bx + ((W0) + r) * 576);                   \
      ACC = __builtin_amdgcn_mfma_f32_16x16x32_bf16(BUF[r].v, b, ACC, 0, 0, 0); \
    } }

  #pragma unroll 1
  for (int t = 0; t < NSTEP; ++t) {
    AF ha[8], hb[8];
    const u16* hp = H + (size_t)t * 65536 + (size_t)arow * 1024 + lk * 8;
    int v0 = AL(FADDR(0));
    int v1 = AL(FADDR(1));
    int v2 = AL(FADDR(2));
    int v3 = AL(FADDR(3));
    f32x4 acx = { bias, bias, bias, bias };
    #pragma unroll
    for (int kk = 0; kk < 8; ++kk) {
      bf16x8 b = *(const bf16x8*)(bx + kk * 576);
      acx = __builtin_amdgcn_mfma_f32_16x16x32_bf16(ax[kk], b, acx, 0, 0, 0);
    }
    WAITV(v0, 0);
    LD8(ha, 0);
    WAITV(v1, 1);
    LD8(hb, 1);
    #pragma unroll
    for (int kk = 8; kk < 16; ++kk) {
      bf16x8 b = *(const bf16x8*)(bx + kk * 576);
      acx = __builtin_amdgcn_mfma_f32_16x16x32_bf16(ax[kk], b, acx, 0, 0, 0);
    }
    f32x4 ac1 = { 0.f, 0.f, 0.f, 0.f };
    f32x4 ac2 = { 0.f, 0.f, 0.f, 0.f };
    MM8(ac1, ha, 16);
    WAITV(v2, 2);
    LD8(ha, 2);
    MM8(ac2, hb, 24);
    WAITV(v3, 3);
    LD8(hb, 3);
    MM8(ac1, ha, 32);
    MM8(ac2, hb, 40);

    float hv4[4], cn4[4];
    #pragma unroll
    for (int r = 0; r < 4; ++r) {
      float xv = acx[r] + ac1[r] + ac2[r];
      float act = sca / (1.f + __expf(-sca * xv)) + bd;
      float gg = __shfl_xor(act, 8);
      float ff = __shfl_xor(act, 4);
      float oo = __shfl_xor(act, 12);
      float cn = ff * cst[r] + act * gg;
      cst[r] = cn;
      float tc = 2.f / (1.f + __expf(-2.f * cn)) - 1.f;
      hv4[r] = oo * tc;
      cn4[r] = cn;
    }

    if (t == NSTEP - 1) {
      if (lr < 4) {
        #pragma unroll
        for (int r = 0; r < 4; ++r) {
          int R = w * 16 + lk * 4 + r;
          out[(size_t)R * 1024 + j * 4 + lr]          = hv4[r];
          out[65536 + (size_t)R * 1024 + j * 4 + lr]  = hv4[r];
          out[131072 + (size_t)R * 1024 + j * 4 + lr] = cn4[r];
        }
      }
    } else {
      if (lr < 4) {
        #pragma unroll
        for (int r = 0; r < 4; ++r) hx[w][lk * 4 + r][lr] = f2bf(hv4[r]);
      }
      if (l < 16) {
        u64 pk = *(const u64*)(&hx[w][l][0]);
        u16* hw = H + (size_t)(t + 1) * 65536 + (size_t)(w * 16 + l) * 1024 + j * 4;
        AS((u64*)hw, pk);
      }
      asm volatile("s_waitcnt vmcnt(0)" ::: "memory");
      if (l == 0) AS(F + j * 128 + w * 32, t + 1);
      {
        const u16* apre = A1 + ((size_t)(t + 1) * 64 + arow) * 512 + lk * 8;
        #pragma unroll
        for (int kk = 0; kk < 16; ++kk) ax[kk] = *(const bf16x8*)(apre + kk * 32);
      }
    }
  }
#undef FADDR
#undef WAITV
#undef LD8
#undef MM8
}

extern "C" void kernel_launch(void* const* d_in, const int* in_sizes, int n_in,
                              void* d_out, int out_size, void* d_ws, size_t ws_size,
                              hipStream_t stream) {
  const int*   sent = (const int*)d_in[0];
  const float* emb  = (const float*)d_in[1];
  const float* w_ih = (const float*)d_in[2];
  const float* w_hh = (const float*)d_in[3];
  const float* b_ih = (const float*)d_in[4];
  const float* b_hh = (const float*)d_in[5];
  float* out = (float*)d_out;

  char* ws = (char*)d_ws;
  u16* A1 = (u16*)ws;                                  // 32 MiB

  // tier A: A1 32Mi + tagged H64 128Mi = 160 MiB
  const size_t needA = 33554432ull + 134217728ull;
  const int tagged = (ws_size >= needA) ? 1 : 0;

  gather_kernel<<<8192, 256, 0, stream>>>(sent, emb, A1);

  if (tagged) {
    u64* H64 = (u64*)(ws + 33554432);
    prepA_kernel<<<4096, 256, 0, stream>>>(H64);
    void* args[] = { (void*)&A1, (void*)&w_ih, (void*)&w_hh,
                     (void*)&b_ih, (void*)&b_hh, (void*)&H64, (void*)&out };
    hipError_t err = hipLaunchCooperativeKernel((void*)lstm_tag_kernel,
                                                dim3(256), dim3(256), args, 0, stream);
    if (err != hipSuccess)
      lstm_tag_kernel<<<dim3(256), dim3(256), 0, stream>>>(A1, w_ih, w_hh,
                                                           b_ih, b_hh, H64, out);
  } else {
    u16* H = (u16*)(ws + 33554432);                    // 512 x 128 KiB
    int* F = (int*)(ws + 33554432 + 67108864);
    prepB_kernel<<<256, 256, 0, stream>>>((u64*)H, F);
    void* args[] = { (void*)&A1, (void*)&w_ih, (void*)&w_hh,
                     (void*)&b_ih, (void*)&b_hh, (void*)&H, (void*)&out, (void*)&F };
    hipError_t err = hipLaunchCooperativeKernel((void*)lstm_fb_kernel,
                                                dim3(256), dim3(256), args, 0, stream);
    if (err != hipSuccess)
      lstm_fb_kernel<<<dim3(256), dim3(256), 0, stream>>>(A1, w_ih, w_hh,
                                                          b_ih, b_hh, H, out, F);
  }
}

// Round 23
// 4073.025 us; speedup vs baseline: 2.3404x; 2.3404x over previous
//
#include <hip/hip_runtime.h>

typedef __bf16 bf16x8 __attribute__((ext_vector_type(8)));
typedef float f32x4 __attribute__((ext_vector_type(4)));
typedef unsigned short u16;
typedef unsigned long long u64;

#define NSTEP 512

#define AL(p)   __hip_atomic_load((p), __ATOMIC_RELAXED, __HIP_MEMORY_SCOPE_AGENT)
#define AS(p,v) __hip_atomic_store((p), (v), __ATOMIC_RELAXED, __HIP_MEMORY_SCOPE_AGENT)

__device__ __forceinline__ u16 f2bf(float f) {
  union { float f; unsigned u; } x; x.f = f;
  return (u16)((x.u + 0x7fffu + ((x.u >> 16) & 1u)) >> 16);
}

// zero h buffer 0 + 1024 per-wave epoch flags (every call -> deterministic replays)
__global__ void prep_kernel(u64* __restrict__ H0, int* __restrict__ F) {
  int i = blockIdx.x * blockDim.x + threadIdx.x;
  if (i < 16384) AS(H0 + i, 0ULL);
  if (i < 32768) AS(&F[i], 0);
}

// A1[t*64+b][512] bf16 embedding gather
__global__ void gather_kernel(const int* __restrict__ sent, const float* __restrict__ emb,
                              u16* __restrict__ A1) {
  int row = blockIdx.x * 4 + (threadIdx.x >> 6);   // t*64+b
  int lane = threadIdx.x & 63;
  int t = row >> 6, b = row & 63;
  int idx = sent[b * 512 + t];
  const float* src = emb + (size_t)idx * 512 + lane * 8;
  u16* dst = A1 + (size_t)row * 512 + lane * 8;
  #pragma unroll
  for (int k = 0; k < 8; ++k) dst[k] = f2bf(src[k]);
}

// 256 WGs x 256 thr. WG j owns h cols [j*4,j*4+4), gates packed rb = g*4+nn = lr.
// Weights in padded LDS. h: per-step FRESH buffers — producers store sc1,
// consumers read cached after flag detect (r12/r15-proven). No grid barrier
// (r15); concurrent flag issue (r16); x-proj 8+8 split + split acc chains (r18).
// NEW (r23): chunk-order rotation by (j&3) — consumers start at different
// K-chunks, spreading flag/line polling across all 4 producer groups instead
// of the whole grid hammering chunk 0 first (peak L3-slice queue depth /4).
__global__ void __launch_bounds__(256, 2)
lstm_kernel(const u16* __restrict__ A1,
            const float* __restrict__ wih, const float* __restrict__ whh,
            const float* __restrict__ bih, const float* __restrict__ bhh,
            u16* __restrict__ H, float* __restrict__ out, int* __restrict__ F) {
  __shared__ u16 wlds[48 * 16 * 36];        // 55296 B, stride-36 pad
  __shared__ alignas(8) u16 hx[4][16][4];   // per-wave h-store packing bounce

  const int j   = blockIdx.x;
  const int tid = threadIdx.x;
  const int w   = tid >> 6;            // wave = batch tile 0..3
  const int l   = tid & 63;
  const int lr  = l & 15, lk = l >> 4;
  const int g   = lr >> 2, nn = lr & 3;
  const int wrow = g * 1024 + j * 4 + nn;

  // ---- stage ALL weights fp32->bf16 into padded LDS (once) ----
  for (int task = tid; task < 3072; task += 256) {
    int kk = task >> 6;                 // K chunk of 32 (0..47)
    int rem = task & 63;
    int rb = rem >> 2, q = rem & 3;
    int row = (rb >> 2) * 1024 + j * 4 + (rb & 3);
    const float* src = (kk < 16) ? (wih + (size_t)row * 512 + kk * 32 + q * 8)
                                 : (whh + (size_t)row * 1024 + (kk - 16) * 32 + q * 8);
    u16* dst = wlds + (kk * 16 + rb) * 36 + q * 8;
    #pragma unroll
    for (int e = 0; e < 8; ++e) dst[e] = f2bf(src[e]);
  }
  __syncthreads();

  const float bias = bih[wrow] + bhh[wrow];
  const float sca = (g == 2) ? 2.f : 1.f;   // tanh-as-sigmoid scaling
  const float bd  = (g == 2) ? -1.f : 0.f;
  const int arow = w * 16 + lr;             // batch row for A fragments
  const u16* bx = wlds + lr * 36 + lk * 8;  // + kk*576 per K chunk

  // rotated chunk order: WG j starts at chunk j&3 (herd de-synchronization)
  const int c0 = j & 3;
  const int c1 = (c0 + 1) & 3;
  const int c2 = (c0 + 2) & 3;
  const int c3 = (c0 + 3) & 3;

  float cst[4] = {0.f, 0.f, 0.f, 0.f};

  // prefetch A1 fragments for t=0
  bf16x8 ax[16];
  {
    const u16* apre = A1 + (size_t)arow * 512 + lk * 8;
    #pragma unroll
    for (int kk = 0; kk < 16; ++kk) ax[kk] = *(const bf16x8*)(apre + kk * 32);
  }

  union AF { bf16x8 v; u64 q[2]; };

  // flag of (producer WG p, wave w) at F[p*128 + w*32]; lane l covers chunk c's
  // producer WG c*64+l.
#define FADDR(c) (F + (((c) * 64 + l) * 128) + w * 32)
#define WAITV(vv, c)                                                        \
  { while (vv < t) { __builtin_amdgcn_s_sleep(1); vv = AL(FADDR(c)); } }
#define LD8(BUF, CH)                                                        \
  { _Pragma("unroll")                                                       \
    for (int r = 0; r < 8; ++r)                                             \
      BUF[r].v = *(const bf16x8*)(hp + (CH) * 256 + r * 32); }
#define MM8(ACC, BUF, CH)                                                   \
  { _Pragma("unroll")                                                       \
    for (int r = 0; r < 8; ++r) {                                           \
      bf16x8 b = *(const bf16x8*)(bx + (16 + (CH) * 8 + r) * 576);          \
      ACC = __builtin_amdgcn_mfma_f32_16x16x32_bf16(BUF[r].v, b, ACC, 0, 0, 0); \
    } }

  #pragma unroll 1
  for (int t = 0; t < NSTEP; ++t) {
    AF ha[8], hb[8];
    const u16* hp = H + (size_t)t * 65536 + (size_t)arow * 1024 + lk * 8;
    // issue all 4 chunk-flag loads concurrently, in rotated order
    int v0 = AL(FADDR(c0));
    int v1 = AL(FADDR(c1));
    int v2 = AL(FADDR(c2));
    int v3 = AL(FADDR(c3));
    // x-proj first half: covers the publish->detect window
    f32x4 acx = { bias, bias, bias, bias };
    #pragma unroll
    for (int kk = 0; kk < 8; ++kk) {
      bf16x8 b = *(const bf16x8*)(bx + kk * 576);
      acx = __builtin_amdgcn_mfma_f32_16x16x32_bf16(ax[kk], b, acx, 0, 0, 0);
    }
    // detect + issue first two chunk fills ASAP (rotated)
    WAITV(v0, c0);
    LD8(ha, c0);
    WAITV(v1, c1);
    LD8(hb, c1);
    // x-proj second half covers the ha/hb fills
    #pragma unroll
    for (int kk = 8; kk < 16; ++kk) {
      bf16x8 b = *(const bf16x8*)(bx + kk * 576);
      acx = __builtin_amdgcn_mfma_f32_16x16x32_bf16(ax[kk], b, acx, 0, 0, 0);
    }
    // h-projection: 2 independent chains, waits woven in (K-sum is commutative)
    f32x4 ac1 = { 0.f, 0.f, 0.f, 0.f };
    f32x4 ac2 = { 0.f, 0.f, 0.f, 0.f };
    MM8(ac1, ha, c0);
    WAITV(v2, c2);
    LD8(ha, c2);
    MM8(ac2, hb, c1);
    WAITV(v3, c3);
    LD8(hb, c3);
    MM8(ac1, ha, c2);
    MM8(ac2, hb, c3);

    // activations + state update; lanes lr<4 own (rows lk*4+r, col lr)
    float hv4[4], cn4[4];
    #pragma unroll
    for (int r = 0; r < 4; ++r) {
      float xv = acx[r] + ac1[r] + ac2[r];
      float act = sca / (1.f + __expf(-sca * xv)) + bd;  // sigmoid / tanh
      float gg = __shfl_xor(act, 8);
      float ff = __shfl_xor(act, 4);
      float oo = __shfl_xor(act, 12);
      float cn = ff * cst[r] + act * gg;   // act = i at lanes lr<4
      cst[r] = cn;
      float tc = 2.f / (1.f + __expf(-2.f * cn)) - 1.f;
      hv4[r] = oo * tc;
      cn4[r] = cn;
    }

    if (t == NSTEP - 1) {
      if (lr < 4) {
        #pragma unroll
        for (int r = 0; r < 4; ++r) {
          int R = w * 16 + lk * 4 + r;
          out[(size_t)R * 1024 + j * 4 + lr]          = hv4[r];
          out[65536 + (size_t)R * 1024 + j * 4 + lr]  = hv4[r];
          out[131072 + (size_t)R * 1024 + j * 4 + lr] = cn4[r];
        }
      }
    } else {
      // pack wave's 16x4 h tile in LDS (same-wave ds ops in-order; no barrier)
      if (lr < 4) {
        #pragma unroll
        for (int r = 0; r < 4; ++r) hx[w][lk * 4 + r][lr] = f2bf(hv4[r]);
      }
      if (l < 16) {
        u64 pk = *(const u64*)(&hx[w][l][0]);
        u16* hw = H + (size_t)(t + 1) * 65536 + (size_t)(w * 16 + l) * 1024 + j * 4;
        AS((u64*)hw, pk);
      }
      // this wave's h stores reach the coherence point, then publish its flag
      asm volatile("s_waitcnt vmcnt(0)" ::: "memory");
      if (l == 0) AS(F + j * 128 + w * 32, t + 1);
      // prefetch A1 for t+1 (fills under next step's flag wait + x-proj)
      {
        const u16* apre = A1 + ((size_t)(t + 1) * 64 + arow) * 512 + lk * 8;
        #pragma unroll
        for (int kk = 0; kk < 16; ++kk) ax[kk] = *(const bf16x8*)(apre + kk * 32);
      }
    }
  }
#undef FADDR
#undef WAITV
#undef LD8
#undef MM8
}

extern "C" void kernel_launch(void* const* d_in, const int* in_sizes, int n_in,
                              void* d_out, int out_size, void* d_ws, size_t ws_size,
                              hipStream_t stream) {
  const int*   sent = (const int*)d_in[0];
  const float* emb  = (const float*)d_in[1];
  const float* w_ih = (const float*)d_in[2];
  const float* w_hh = (const float*)d_in[3];
  const float* b_ih = (const float*)d_in[4];
  const float* b_hh = (const float*)d_in[5];
  float* out = (float*)d_out;

  // A1 32Mi | H 512 x 128Ki = 64Mi | F 128Ki  (~96.2 MiB; proven available)
  char* ws = (char*)d_ws;
  u16* A1 = (u16*)ws;
  u16* H  = (u16*)(ws + 33554432);
  int* F  = (int*)(ws + 33554432 + 67108864);

  prep_kernel<<<256, 256, 0, stream>>>((u64*)H, F);
  gather_kernel<<<8192, 256, 0, stream>>>(sent, emb, A1);

  void* args[] = { (void*)&A1, (void*)&w_ih, (void*)&w_hh,
                   (void*)&b_ih, (void*)&b_hh, (void*)&H, (void*)&out, (void*)&F };
  hipError_t err = hipLaunchCooperativeKernel((void*)lstm_kernel, dim3(256), dim3(256),
                                              args, 0, stream);
  if (err != hipSuccess) {
    // dataflow kernel needs co-residency only; 2-blocks/CU envelope on 256 CUs
    lstm_kernel<<<dim3(256), dim3(256), 0, stream>>>(A1, w_ih, w_hh, b_ih, b_hh,
                                                     H, out, F);
  }
}